// Round 1
// baseline (543.436 us; speedup 1.0000x reference)
//
#include <hip/hip_runtime.h>
#include <hip/hip_bf16.h>

#define B_ 4
#define T_ 4096
#define FIN 229
#define D_ 256
#define O_ 88
#define K_ 31
#define G_ 8
#define PAD 15
#define LN_EPS 1e-5f

#define WT_SZ (3*FIN*D_)
#define ROWSTOT (B_*T_)
#define MAT_SZ (ROWSTOT*D_)

// ---------------- transpose weights: W[d][f] -> Wt[m][f][d] ----------------
__global__ __launch_bounds__(256) void transpose_w(
    const float* __restrict__ Wq, const float* __restrict__ Wk,
    const float* __restrict__ Wv, float* __restrict__ Wt) {
  int f = blockIdx.x;      // 0..228
  int d = threadIdx.x;     // 0..255
  Wt[(0*FIN + f)*D_ + d] = Wq[d*FIN + f];
  Wt[(1*FIN + f)*D_ + d] = Wk[d*FIN + f];
  Wt[(2*FIN + f)*D_ + d] = Wv[d*FIN + f];
}

// ---------------- fused Q/K/V projection GEMM ----------------
#define PR 8
__global__ __launch_bounds__(256) void proj_qkv(
    const float* __restrict__ spec, const float* __restrict__ Wt,
    float* __restrict__ qo, float* __restrict__ ko, float* __restrict__ vo) {
  __shared__ float sp[PR][232];   // stride 232 floats = 928B, 16B aligned rows
  long row0 = (long)blockIdx.x * PR;
  int tid = threadIdx.x;
  for (int idx = tid; idx < PR*FIN; idx += 256) {
    int r = idx / FIN, f = idx - r*FIN;
    sp[r][f] = spec[(row0 + r)*FIN + f];
  }
  __syncthreads();
  int d = tid;
  float aq[PR], ak[PR], av[PR];
  #pragma unroll
  for (int r = 0; r < PR; ++r) { aq[r]=0.f; ak[r]=0.f; av[r]=0.f; }
  const float* Wqt = Wt;
  const float* Wkt = Wt + FIN*D_;
  const float* Wvt = Wt + 2*FIN*D_;
  int f = 0;
  for (; f + 4 <= FIN; f += 4) {
    float wq[4], wk[4], wv[4];
    #pragma unroll
    for (int i = 0; i < 4; ++i) {
      wq[i] = Wqt[(f+i)*D_ + d];
      wk[i] = Wkt[(f+i)*D_ + d];
      wv[i] = Wvt[(f+i)*D_ + d];
    }
    #pragma unroll
    for (int r = 0; r < PR; ++r) {
      float4 s4 = *reinterpret_cast<const float4*>(&sp[r][f]);
      aq[r] += s4.x*wq[0] + s4.y*wq[1] + s4.z*wq[2] + s4.w*wq[3];
      ak[r] += s4.x*wk[0] + s4.y*wk[1] + s4.z*wk[2] + s4.w*wk[3];
      av[r] += s4.x*wv[0] + s4.y*wv[1] + s4.z*wv[2] + s4.w*wv[3];
    }
  }
  for (; f < FIN; ++f) {
    float wq = Wqt[f*D_ + d], wk = Wkt[f*D_ + d], wv = Wvt[f*D_ + d];
    #pragma unroll
    for (int r = 0; r < PR; ++r) {
      float s = sp[r][f];
      aq[r] += s*wq; ak[r] += s*wk; av[r] += s*wv;
    }
  }
  #pragma unroll
  for (int r = 0; r < PR; ++r) {
    long o = (row0 + r)*D_ + d;
    qo[o] = aq[r]; ko[o] = ak[r]; vo[o] = av[r];
  }
}

// ---------------- fused attention + LN + linear + sigmoid ----------------
__global__ __launch_bounds__(256) void attn_fused(
    const float* __restrict__ q, const float* __restrict__ k, const float* __restrict__ v,
    const float* __restrict__ rel, const float* __restrict__ ln_g, const float* __restrict__ ln_b,
    const float* __restrict__ lw, const float* __restrict__ lb,
    float* __restrict__ frame_out, float* __restrict__ attn_out) {
  int bt = blockIdx.x;            // 0..16383
  int b = bt >> 12;               // T = 4096
  int t = bt & (T_ - 1);
  int tid = threadIdx.x;
  int g = tid >> 5, j = tid & 31;
  __shared__ float eS[G_][33];
  __shared__ float aS[G_][33];
  __shared__ float hS[D_];
  __shared__ float r1[4], r2[4];

  long base = (long)bt * D_;
  float qd = q[base + tid];
  const float* relRow = rel + tid * K_;
  long rowB = (long)b * T_;

  // energy: e[g][kp] = sum_{d in group} q_d * (k[t'][d] + rel[d][kp])
  for (int kp = 0; kp < K_; ++kp) {
    int tp = t + kp - PAD;
    float kv = 0.f;
    if ((unsigned)tp < (unsigned)T_) kv = k[(rowB + tp)*D_ + tid];
    float e = qd * (kv + relRow[kp]);
    e += __shfl_xor(e, 16); e += __shfl_xor(e, 8); e += __shfl_xor(e, 4);
    e += __shfl_xor(e, 2);  e += __shfl_xor(e, 1);
    if (j == 0) eS[g][kp] = e;
  }
  __syncthreads();

  // softmax over K within each group (lanes 0..30 hold the values)
  float ev = (j < K_) ? eS[g][j] : -3.4e38f;
  float m = ev;
  m = fmaxf(m, __shfl_xor(m, 16)); m = fmaxf(m, __shfl_xor(m, 8));
  m = fmaxf(m, __shfl_xor(m, 4));  m = fmaxf(m, __shfl_xor(m, 2));
  m = fmaxf(m, __shfl_xor(m, 1));
  float ex = (j < K_) ? __expf(ev - m) : 0.f;
  float s = ex;
  s += __shfl_xor(s, 16); s += __shfl_xor(s, 8); s += __shfl_xor(s, 4);
  s += __shfl_xor(s, 2);  s += __shfl_xor(s, 1);
  float a = ex / s;
  if (j < K_) {
    aS[g][j] = a;
    attn_out[((long)bt*G_ + g)*K_ + j] = a;
  }
  __syncthreads();

  // PV: out_d = sum_kp attn[g][kp] * v[t'][d]
  float outd = 0.f;
  for (int kp = 0; kp < K_; ++kp) {
    int tp = t + kp - PAD;
    if ((unsigned)tp < (unsigned)T_) {
      outd += aS[g][kp] * v[(rowB + tp)*D_ + tid];
    }
  }

  // LayerNorm over D=256 (block reduction)
  float s1 = outd, s2 = outd * outd;
  s1 += __shfl_xor(s1, 32); s2 += __shfl_xor(s2, 32);
  s1 += __shfl_xor(s1, 16); s2 += __shfl_xor(s2, 16);
  s1 += __shfl_xor(s1, 8);  s2 += __shfl_xor(s2, 8);
  s1 += __shfl_xor(s1, 4);  s2 += __shfl_xor(s2, 4);
  s1 += __shfl_xor(s1, 2);  s2 += __shfl_xor(s2, 2);
  s1 += __shfl_xor(s1, 1);  s2 += __shfl_xor(s2, 1);
  int wave = tid >> 6;
  if ((tid & 63) == 0) { r1[wave] = s1; r2[wave] = s2; }
  __syncthreads();
  s1 = r1[0] + r1[1] + r1[2] + r1[3];
  s2 = r2[0] + r2[1] + r2[2] + r2[3];
  float mu = s1 * (1.f/D_);
  float var = s2 * (1.f/D_) - mu*mu;
  float inv = rsqrtf(var + LN_EPS);
  float h = (outd - mu) * inv * ln_g[tid] + ln_b[tid];
  hS[tid] = h;
  __syncthreads();

  // final linear + sigmoid: group g computes outputs o = g*11 .. g*11+10
  #pragma unroll
  for (int oi = 0; oi < 11; ++oi) {
    int o = g*11 + oi;
    float acc = 0.f;
    #pragma unroll
    for (int c = 0; c < 8; ++c) {
      int dd = j + 32*c;
      acc += hS[dd] * lw[o*D_ + dd];
    }
    acc += __shfl_xor(acc, 16); acc += __shfl_xor(acc, 8); acc += __shfl_xor(acc, 4);
    acc += __shfl_xor(acc, 2);  acc += __shfl_xor(acc, 1);
    if (j == 0) {
      float z = acc + lb[o];
      frame_out[(long)bt*O_ + o] = 1.f / (1.f + __expf(-z));
    }
  }
}

extern "C" void kernel_launch(void* const* d_in, const int* in_sizes, int n_in,
                              void* d_out, int out_size, void* d_ws, size_t ws_size,
                              hipStream_t stream) {
  const float* spec = (const float*)d_in[0];
  const float* Wq   = (const float*)d_in[1];
  const float* Wk   = (const float*)d_in[2];
  const float* Wv   = (const float*)d_in[3];
  const float* rel  = (const float*)d_in[4];
  const float* lng  = (const float*)d_in[5];
  const float* lnb  = (const float*)d_in[6];
  const float* lw   = (const float*)d_in[7];
  const float* lb   = (const float*)d_in[8];

  float* out   = (float*)d_out;
  float* frame = out;                          // B*T*O
  float* attn  = out + (long)B_*T_*O_;         // B*T*G*K

  float* ws = (float*)d_ws;
  float* Wt = ws;
  float* qb = ws + WT_SZ;
  float* kb = qb + MAT_SZ;
  float* vb = kb + MAT_SZ;

  transpose_w<<<FIN, 256, 0, stream>>>(Wq, Wk, Wv, Wt);
  proj_qkv<<<ROWSTOT/PR, 256, 0, stream>>>(spec, Wt, qb, kb, vb);
  attn_fused<<<ROWSTOT, 256, 0, stream>>>(qb, kb, vb, rel, lng, lnb, lw, lb, frame, attn);
}